// Round 1
// baseline (149.365 us; speedup 1.0000x reference)
//
#include <hip/hip_runtime.h>
#include <math.h>

// Problem constants (from reference): B=4, M=4096, D=64, W=128
constexpr int B = 4;
constexpr int M = 4096;
constexpr int D = 64;
constexpr int W = 128;

// One block per (b, m) row. 128 threads = 2 waves.
//  - b = blockIdx & 3 so each XCD (round-robin blockIdx % 8) sees one batch
//    -> per-XCD gather working set ~3 MiB fits 4 MiB L2.
__global__ __launch_bounds__(128) void sparse_attn_kernel(
    const float* __restrict__ q,
    const float* __restrict__ k,
    const float* __restrict__ v,
    const int*   __restrict__ idx,
    float*       __restrict__ out)
{
    const int blk = blockIdx.x;
    const int b = blk & 3;
    const int m = blk >> 2;
    const int t = threadIdx.x;      // 0..127
    const int lane = t & 63;
    const int wave = t >> 6;        // 0 or 1

    __shared__ float q_s[D];
    __shared__ int   idx_s[W];
    __shared__ float p_s[W];
    __shared__ float red_s[4];
    __shared__ float out_part[D];

    // Stage indices and q row.
    idx_s[t] = idx[m * W + t];
    if (t < D) q_s[t] = q[((size_t)b * M + m) * D + t];
    __syncthreads();

    // ---- logits: thread t owns column w = t ----
    const float* kb = k + (size_t)b * M * D;
    const float4* krow = (const float4*)(kb + (size_t)idx_s[t] * D);
    float logit = 0.f;
    #pragma unroll
    for (int i = 0; i < D / 4; ++i) {
        float4 kv = krow[i];
        logit += kv.x * q_s[4*i+0];
        logit += kv.y * q_s[4*i+1];
        logit += kv.z * q_s[4*i+2];
        logit += kv.w * q_s[4*i+3];
    }

    // ---- softmax over 128 threads ----
    float mx = logit;
    #pragma unroll
    for (int o = 1; o < 64; o <<= 1) mx = fmaxf(mx, __shfl_xor(mx, o));
    if (lane == 0) red_s[wave] = mx;
    __syncthreads();
    mx = fmaxf(red_s[0], red_s[1]);

    float e = __expf(logit - mx);
    float sm = e;
    #pragma unroll
    for (int o = 1; o < 64; o <<= 1) sm += __shfl_xor(sm, o);
    if (lane == 0) red_s[2 + wave] = sm;
    __syncthreads();
    const float denom = red_s[2] + red_s[3];

    p_s[t] = e / denom;
    __syncthreads();

    // ---- output: lane = d; wave 0 covers w in [0,64), wave 1 in [64,128) ----
    const float* vb = v + (size_t)b * M * D;
    const int d = lane;
    float acc = 0.f;
    const int w0 = wave * 64;
    #pragma unroll 16
    for (int w = w0; w < w0 + 64; ++w) {
        acc += p_s[w] * vb[(size_t)idx_s[w] * D + d];
    }

    if (wave == 0) out_part[d] = acc;
    __syncthreads();
    if (wave == 1) out[((size_t)b * M + m) * D + d] = out_part[d] + acc;
}

extern "C" void kernel_launch(void* const* d_in, const int* in_sizes, int n_in,
                              void* d_out, int out_size, void* d_ws, size_t ws_size,
                              hipStream_t stream) {
    const float* q = (const float*)d_in[0];
    const float* k = (const float*)d_in[1];
    const float* v = (const float*)d_in[2];
    const int* idx = (const int*)d_in[3];
    float* out = (float*)d_out;

    dim3 grid(B * M);
    dim3 block(128);
    sparse_attn_kernel<<<grid, block, 0, stream>>>(q, k, v, idx, out);
}

// Round 2
// 117.964 us; speedup vs baseline: 1.2662x; 1.2662x over previous
//
#include <hip/hip_runtime.h>
#include <math.h>

// Problem constants: B=4, M=4096, D=64, W=128
constexpr int B = 4;
constexpr int M = 4096;
constexpr int D = 64;
constexpr int W = 128;

// One block per (b, m) row, 128 threads = 2 waves.
// Gather pattern: 16 lanes cooperate on one row (lane ci loads float4 chunk ci),
// so each wave-level load covers 4 complete rows = 16 fully-used 64B lines
// (vs 64 sparse lines in the row-per-thread layout).
__global__ __launch_bounds__(128) void sparse_attn_kernel(
    const float* __restrict__ q,
    const float* __restrict__ k,
    const float* __restrict__ v,
    const int*   __restrict__ idx,
    float*       __restrict__ out)
{
    const int blk = blockIdx.x;
    const int b = blk & 3;        // batch round-robins with XCD assignment
    const int m = blk >> 2;
    const int t = threadIdx.x;    // 0..127
    const int lane = t & 63;
    const int wave = t >> 6;      // 0 or 1
    const int ci = lane & 15;     // float4 chunk within a row (D=64 -> 16 chunks)
    const int r  = lane >> 4;     // row-within-group 0..3

    __shared__ int   idx_s[W];
    __shared__ float logit_s[W];
    __shared__ float p_s[W];
    __shared__ float red_s[4];
    __shared__ float4 opart_s[16];

    idx_s[t] = idx[m * W + t];
    const float4 qf = ((const float4*)(q + ((size_t)b * M + m) * D))[ci];
    __syncthreads();

    const float* kb = k + (size_t)b * M * D;
    const int wbase = wave * 64;

    // ---- logits: 4 rows per iteration per wave, coalesced float4 loads ----
    #pragma unroll
    for (int j = 0; j < 16; ++j) {
        const int w = wbase + j * 4 + r;
        const float4 kv = ((const float4*)(kb + (size_t)idx_s[w] * D))[ci];
        float part = kv.x * qf.x + kv.y * qf.y + kv.z * qf.z + kv.w * qf.w;
        // reduce over the 16 lanes of this row group (DPP-able xor masks)
        part += __shfl_xor(part, 1);
        part += __shfl_xor(part, 2);
        part += __shfl_xor(part, 4);
        part += __shfl_xor(part, 8);
        if (ci == 0) logit_s[w] = part;
    }
    __syncthreads();

    // ---- softmax over W=128, thread t <-> column t ----
    float logit = logit_s[t];
    float mx = logit;
    #pragma unroll
    for (int o = 1; o < 64; o <<= 1) mx = fmaxf(mx, __shfl_xor(mx, o));
    if (lane == 0) red_s[wave] = mx;
    __syncthreads();
    mx = fmaxf(red_s[0], red_s[1]);

    float e = __expf(logit - mx);
    float sm = e;
    #pragma unroll
    for (int o = 1; o < 64; o <<= 1) sm += __shfl_xor(sm, o);
    if (lane == 0) red_s[2 + wave] = sm;
    __syncthreads();
    const float inv_denom = 1.0f / (red_s[2] + red_s[3]);
    p_s[t] = e * inv_denom;
    __syncthreads();

    // ---- output: same 4-rows-per-inst pattern on v ----
    const float* vb = v + (size_t)b * M * D;
    float4 acc = {0.f, 0.f, 0.f, 0.f};
    #pragma unroll
    for (int j = 0; j < 16; ++j) {
        const int w = wbase + j * 4 + r;
        const float p = p_s[w];
        const float4 vv = ((const float4*)(vb + (size_t)idx_s[w] * D))[ci];
        acc.x += p * vv.x;
        acc.y += p * vv.y;
        acc.z += p * vv.z;
        acc.w += p * vv.w;
    }
    // reduce across the 4 row-groups (lanes xor 16, 32)
    acc.x += __shfl_xor(acc.x, 16);
    acc.y += __shfl_xor(acc.y, 16);
    acc.z += __shfl_xor(acc.z, 16);
    acc.w += __shfl_xor(acc.w, 16);
    acc.x += __shfl_xor(acc.x, 32);
    acc.y += __shfl_xor(acc.y, 32);
    acc.z += __shfl_xor(acc.z, 32);
    acc.w += __shfl_xor(acc.w, 32);

    if (wave == 0 && r == 0) opart_s[ci] = acc;
    __syncthreads();
    if (wave == 1 && r == 0) {
        const float4 o0 = opart_s[ci];
        float4 res;
        res.x = o0.x + acc.x;
        res.y = o0.y + acc.y;
        res.z = o0.z + acc.z;
        res.w = o0.w + acc.w;
        ((float4*)(out + ((size_t)b * M + m) * D))[ci] = res;
    }
}

extern "C" void kernel_launch(void* const* d_in, const int* in_sizes, int n_in,
                              void* d_out, int out_size, void* d_ws, size_t ws_size,
                              hipStream_t stream) {
    const float* q = (const float*)d_in[0];
    const float* k = (const float*)d_in[1];
    const float* v = (const float*)d_in[2];
    const int* idx = (const int*)d_in[3];
    float* out = (float*)d_out;

    dim3 grid(B * M);
    dim3 block(128);
    sparse_attn_kernel<<<grid, block, 0, stream>>>(q, k, v, idx, out);
}

// Round 3
// 100.746 us; speedup vs baseline: 1.4826x; 1.1709x over previous
//
#include <hip/hip_runtime.h>
#include <hip/hip_fp16.h>
#include <math.h>

// Problem constants: B=4, M=4096, D=64, W=128
constexpr int B = 4;
constexpr int M = 4096;
constexpr int D = 64;
constexpr int W = 128;
constexpr int NELEM = B * M * D;   // 1,048,576 per tensor

// ---- pass 1: fp32 -> fp16 conversion of k and v into workspace ----
__global__ __launch_bounds__(256) void cvt_f32_f16(const float4* __restrict__ src,
                                                   __half2* __restrict__ dst, int n4) {
    int i = blockIdx.x * 256 + threadIdx.x;
    if (i < n4) {
        float4 f = src[i];
        dst[2 * i]     = __floats2half2_rn(f.x, f.y);
        dst[2 * i + 1] = __floats2half2_rn(f.z, f.w);
    }
}

// ---- main kernel (fp16 k/v): one block per (b,m), 128 threads = 2 waves ----
// Gather: 8 lanes per row (lane ci loads 16B = 8 halves), so one wave-inst
// covers 8 complete rows = 16 fully-used 64B lines. All 8 loads of a phase
// are batched into registers before any consumption (deep vmcnt pipeline).
__global__ __launch_bounds__(128, 8) void sparse_attn_f16(
    const float* __restrict__ q,
    const __half* __restrict__ kh,
    const __half* __restrict__ vh,
    const int*   __restrict__ idx,
    float*       __restrict__ out)
{
    const int blk = blockIdx.x;
    const int b = blk & 3;        // batch round-robins with XCD assignment
    const int m = blk >> 2;
    const int t = threadIdx.x;
    const int lane = t & 63;
    const int wave = t >> 6;
    const int ci = lane & 7;      // 16B chunk within row (D=64 halves -> 8 chunks)
    const int r  = lane >> 3;     // row-within-group 0..7

    __shared__ int    idx_s[W];
    __shared__ float  sc_s[W];    // logits, then softmax probs
    __shared__ float  red_s[4];
    __shared__ float4 opart4[16];

    idx_s[t] = idx[m * W + t];
    const float4* qrow = (const float4*)(q + ((size_t)b * M + m) * D);
    const float4 qa = qrow[2 * ci];
    const float4 qb = qrow[2 * ci + 1];
    __syncthreads();

    const __half* kb = kh + (size_t)b * M * D;
    const __half* vb = vh + (size_t)b * M * D;
    const int wbase = wave * 64;

    // ---- logits ----
    float4 kreg[8];
    #pragma unroll
    for (int j = 0; j < 8; ++j) {
        const int w = wbase + j * 8 + r;
        kreg[j] = ((const float4*)(kb + (size_t)idx_s[w] * D))[ci];
    }
    #pragma unroll
    for (int j = 0; j < 8; ++j) {
        const int w = wbase + j * 8 + r;
        const __half2* h = (const __half2*)&kreg[j];
        float2 f0 = __half22float2(h[0]);
        float2 f1 = __half22float2(h[1]);
        float2 f2 = __half22float2(h[2]);
        float2 f3 = __half22float2(h[3]);
        float part = f0.x * qa.x + f0.y * qa.y + f1.x * qa.z + f1.y * qa.w
                   + f2.x * qb.x + f2.y * qb.y + f3.x * qb.z + f3.y * qb.w;
        part += __shfl_xor(part, 1);
        part += __shfl_xor(part, 2);
        part += __shfl_xor(part, 4);
        if (ci == 0) sc_s[w] = part;
    }
    __syncthreads();

    // ---- softmax over W=128, thread t <-> column t ----
    float logit = sc_s[t];
    float mx = logit;
    #pragma unroll
    for (int o = 1; o < 64; o <<= 1) mx = fmaxf(mx, __shfl_xor(mx, o));
    if (lane == 0) red_s[wave] = mx;
    __syncthreads();
    mx = fmaxf(red_s[0], red_s[1]);
    float e = __expf(logit - mx);
    float sm = e;
    #pragma unroll
    for (int o = 1; o < 64; o <<= 1) sm += __shfl_xor(sm, o);
    if (lane == 0) red_s[2 + wave] = sm;
    __syncthreads();
    const float inv = 1.0f / (red_s[2] + red_s[3]);
    sc_s[t] = e * inv;
    __syncthreads();

    // ---- output: lane ci owns dims [ci*8, ci*8+8), 8 rows per inst ----
    float4 vreg[8];
    #pragma unroll
    for (int j = 0; j < 8; ++j) {
        const int w = wbase + j * 8 + r;
        vreg[j] = ((const float4*)(vb + (size_t)idx_s[w] * D))[ci];
    }
    float acc[8] = {0, 0, 0, 0, 0, 0, 0, 0};
    #pragma unroll
    for (int j = 0; j < 8; ++j) {
        const int w = wbase + j * 8 + r;
        const float p = sc_s[w];
        const __half2* h = (const __half2*)&vreg[j];
        #pragma unroll
        for (int c = 0; c < 4; ++c) {
            float2 f = __half22float2(h[c]);
            acc[2 * c]     += p * f.x;
            acc[2 * c + 1] += p * f.y;
        }
    }
    #pragma unroll
    for (int o = 8; o < 64; o <<= 1) {
        #pragma unroll
        for (int i = 0; i < 8; ++i) acc[i] += __shfl_xor(acc[i], o);
    }
    if (wave == 0 && r == 0) {
        opart4[2 * ci]     = make_float4(acc[0], acc[1], acc[2], acc[3]);
        opart4[2 * ci + 1] = make_float4(acc[4], acc[5], acc[6], acc[7]);
    }
    __syncthreads();
    if (wave == 1 && r == 0) {
        float4 o0 = opart4[2 * ci];
        float4 o1 = opart4[2 * ci + 1];
        float4* orow = (float4*)(out + ((size_t)b * M + m) * D);
        orow[2 * ci]     = make_float4(o0.x + acc[0], o0.y + acc[1],
                                       o0.z + acc[2], o0.w + acc[3]);
        orow[2 * ci + 1] = make_float4(o1.x + acc[4], o1.y + acc[5],
                                       o1.z + acc[6], o1.w + acc[7]);
    }
}

// ---- fallback fp32 kernel (R1) if workspace is too small ----
__global__ __launch_bounds__(128) void sparse_attn_f32(
    const float* __restrict__ q,
    const float* __restrict__ k,
    const float* __restrict__ v,
    const int*   __restrict__ idx,
    float*       __restrict__ out)
{
    const int blk = blockIdx.x;
    const int b = blk & 3;
    const int m = blk >> 2;
    const int t = threadIdx.x;
    const int lane = t & 63;
    const int wave = t >> 6;
    const int ci = lane & 15;
    const int r  = lane >> 4;

    __shared__ int   idx_s[W];
    __shared__ float sc_s[W];
    __shared__ float red_s[4];
    __shared__ float4 opart_s[16];

    idx_s[t] = idx[m * W + t];
    const float4 qf = ((const float4*)(q + ((size_t)b * M + m) * D))[ci];
    __syncthreads();

    const float* kb = k + (size_t)b * M * D;
    const int wbase = wave * 64;

    #pragma unroll
    for (int j = 0; j < 16; ++j) {
        const int w = wbase + j * 4 + r;
        const float4 kv = ((const float4*)(kb + (size_t)idx_s[w] * D))[ci];
        float part = kv.x * qf.x + kv.y * qf.y + kv.z * qf.z + kv.w * qf.w;
        part += __shfl_xor(part, 1);
        part += __shfl_xor(part, 2);
        part += __shfl_xor(part, 4);
        part += __shfl_xor(part, 8);
        if (ci == 0) sc_s[w] = part;
    }
    __syncthreads();

    float logit = sc_s[t];
    float mx = logit;
    #pragma unroll
    for (int o = 1; o < 64; o <<= 1) mx = fmaxf(mx, __shfl_xor(mx, o));
    if (lane == 0) red_s[wave] = mx;
    __syncthreads();
    mx = fmaxf(red_s[0], red_s[1]);
    float e = __expf(logit - mx);
    float sm = e;
    #pragma unroll
    for (int o = 1; o < 64; o <<= 1) sm += __shfl_xor(sm, o);
    if (lane == 0) red_s[2 + wave] = sm;
    __syncthreads();
    const float inv_denom = 1.0f / (red_s[2] + red_s[3]);
    sc_s[t] = e * inv_denom;
    __syncthreads();

    const float* vb = v + (size_t)b * M * D;
    float4 acc = {0.f, 0.f, 0.f, 0.f};
    #pragma unroll
    for (int j = 0; j < 16; ++j) {
        const int w = wbase + j * 4 + r;
        const float p = sc_s[w];
        const float4 vv = ((const float4*)(vb + (size_t)idx_s[w] * D))[ci];
        acc.x += p * vv.x; acc.y += p * vv.y;
        acc.z += p * vv.z; acc.w += p * vv.w;
    }
    acc.x += __shfl_xor(acc.x, 16); acc.y += __shfl_xor(acc.y, 16);
    acc.z += __shfl_xor(acc.z, 16); acc.w += __shfl_xor(acc.w, 16);
    acc.x += __shfl_xor(acc.x, 32); acc.y += __shfl_xor(acc.y, 32);
    acc.z += __shfl_xor(acc.z, 32); acc.w += __shfl_xor(acc.w, 32);

    if (wave == 0 && r == 0) opart_s[ci] = acc;
    __syncthreads();
    if (wave == 1 && r == 0) {
        const float4 o0 = opart_s[ci];
        float4 res;
        res.x = o0.x + acc.x; res.y = o0.y + acc.y;
        res.z = o0.z + acc.z; res.w = o0.w + acc.w;
        ((float4*)(out + ((size_t)b * M + m) * D))[ci] = res;
    }
}

extern "C" void kernel_launch(void* const* d_in, const int* in_sizes, int n_in,
                              void* d_out, int out_size, void* d_ws, size_t ws_size,
                              hipStream_t stream) {
    const float* q = (const float*)d_in[0];
    const float* k = (const float*)d_in[1];
    const float* v = (const float*)d_in[2];
    const int* idx = (const int*)d_in[3];
    float* out = (float*)d_out;

    const size_t need = (size_t)2 * NELEM * sizeof(__half);  // 4 MiB
    if (ws_size >= need) {
        __half* kh = (__half*)d_ws;
        __half* vh = kh + NELEM;
        const int n4 = NELEM / 4;
        const int cblk = (n4 + 255) / 256;
        cvt_f32_f16<<<cblk, 256, 0, stream>>>((const float4*)k, (__half2*)kh, n4);
        cvt_f32_f16<<<cblk, 256, 0, stream>>>((const float4*)v, (__half2*)vh, n4);
        sparse_attn_f16<<<B * M, 128, 0, stream>>>(q, kh, vh, idx, out);
    } else {
        sparse_attn_f32<<<B * M, 128, 0, stream>>>(q, k, v, idx, out);
    }
}

// Round 5
// 95.991 us; speedup vs baseline: 1.5560x; 1.0495x over previous
//
#include <hip/hip_runtime.h>
#include <hip/hip_fp16.h>
#include <math.h>

// Problem constants: B=4, M=4096, D=64, W=128
constexpr int B = 4;
constexpr int M = 4096;
constexpr int D = 64;
constexpr int W = 128;
constexpr int NELEM = B * M * D;   // 1,048,576 per tensor

// ---- pass 1: fp32 -> fp16 of k AND v in a single launch ----
__global__ __launch_bounds__(256) void cvt_f32_f16_2(
    const float4* __restrict__ k, const float4* __restrict__ v,
    __half2* __restrict__ kh, __half2* __restrict__ vh, int n4) {
    int i = blockIdx.x * 256 + threadIdx.x;
    const float4* src;
    __half2* dst;
    if (i < n4) { src = k; dst = kh; }
    else        { src = v; dst = vh; i -= n4; if (i >= n4) return; }
    float4 f = src[i];
    dst[2 * i]     = __floats2half2_rn(f.x, f.y);
    dst[2 * i + 1] = __floats2half2_rn(f.z, f.w);
}

// ---- main kernel: one WAVE per (b,m) row; 4 waves (4 m-rows) per block ----
// Grid = B * M / 4 blocks (each block covers 4 consecutive m for one b).
// Lane (ci, r): ci = lane&7 owns 16B chunk ci of a row; r = lane>>3 covers
// rows w ≡ r (mod 8). One wave-inst gathers 8 complete fp16 rows = 16 full
// 64B lines. After the single initial barrier, waves are fully independent:
// softmax is done in-register (butterfly over lanes), no LDS round-trips.
__global__ __launch_bounds__(256, 4) void sparse_attn_f16(
    const float* __restrict__ q,
    const __half* __restrict__ kh,
    const __half* __restrict__ vh,
    const int*   __restrict__ idx,
    float*       __restrict__ out)
{
    const int blk  = blockIdx.x;
    const int b    = blk & 3;              // XCD round-robin (blk%8) -> fixed b per XCD
    const int mb   = (blk >> 2) * 4;       // 4 consecutive m rows per block
    const int t    = threadIdx.x;
    const int wave = t >> 6;
    const int lane = t & 63;
    const int ci   = lane & 7;
    const int r    = lane >> 3;
    const int m    = mb + wave;

    __shared__ int idx_s[4 * W];           // 4 rows x 128 indices

    // Stage the 4 rows of column indices (256 lanes x int2 = 512 ints).
    ((int2*)idx_s)[t] = ((const int2*)(idx + (size_t)mb * W))[t];

    // q chunk for this lane (fp32, 32B): dims [ci*8, ci*8+8)
    const float* qrow = q + ((size_t)b * M + m) * D;
    const float4 qa = ((const float4*)qrow)[2 * ci];
    const float4 qb = ((const float4*)qrow)[2 * ci + 1];

    __syncthreads();   // the only barrier

    // Precompute the 16 gathered row indices this lane touches (w = j*8 + r).
    int off[16];
    #pragma unroll
    for (int j = 0; j < 16; ++j) off[j] = idx_s[wave * W + j * 8 + r];

    const __half* kb = kh + (size_t)b * M * D;
    const __half* vb = vh + (size_t)b * M * D;

    // ---- logits: 16 gather insts in 2 register batches of 8 ----
    float larr[16];
    #pragma unroll
    for (int batch = 0; batch < 2; ++batch) {
        float4 kreg[8];
        #pragma unroll
        for (int jj = 0; jj < 8; ++jj) {
            const int j = batch * 8 + jj;
            kreg[jj] = *(const float4*)(kb + (size_t)off[j] * D + ci * 8);
        }
        #pragma unroll
        for (int jj = 0; jj < 8; ++jj) {
            const __half2* h = (const __half2*)&kreg[jj];
            float2 f0 = __half22float2(h[0]);
            float2 f1 = __half22float2(h[1]);
            float2 f2 = __half22float2(h[2]);
            float2 f3 = __half22float2(h[3]);
            float part = f0.x * qa.x + f0.y * qa.y + f1.x * qa.z + f1.y * qa.w
                       + f2.x * qb.x + f2.y * qb.y + f3.x * qb.z + f3.y * qb.w;
            // reduce over the 8 chunk-lanes of this row (butterfly: all hold it)
            part += __shfl_xor(part, 1);
            part += __shfl_xor(part, 2);
            part += __shfl_xor(part, 4);
            larr[batch * 8 + jj] = part;   // lane holds logit for w = j*8 + r
        }
    }

    // ---- softmax, fully in-register ----
    float mx = larr[0];
    #pragma unroll
    for (int j = 1; j < 16; ++j) mx = fmaxf(mx, larr[j]);
    mx = fmaxf(mx, __shfl_xor(mx, 8));
    mx = fmaxf(mx, __shfl_xor(mx, 16));
    mx = fmaxf(mx, __shfl_xor(mx, 32));

    float sum = 0.f;
    #pragma unroll
    for (int j = 0; j < 16; ++j) { larr[j] = __expf(larr[j] - mx); sum += larr[j]; }
    sum += __shfl_xor(sum, 8);
    sum += __shfl_xor(sum, 16);
    sum += __shfl_xor(sum, 32);
    const float inv = 1.0f / sum;   // folded into the final store

    // ---- weighted V gather-accumulate ----
    float acc[8] = {0, 0, 0, 0, 0, 0, 0, 0};
    #pragma unroll
    for (int batch = 0; batch < 2; ++batch) {
        float4 vreg[8];
        #pragma unroll
        for (int jj = 0; jj < 8; ++jj) {
            const int j = batch * 8 + jj;
            vreg[jj] = *(const float4*)(vb + (size_t)off[j] * D + ci * 8);
        }
        #pragma unroll
        for (int jj = 0; jj < 8; ++jj) {
            const float p = larr[batch * 8 + jj];
            const __half2* h = (const __half2*)&vreg[jj];
            #pragma unroll
            for (int c = 0; c < 4; ++c) {
                float2 f = __half22float2(h[c]);
                acc[2 * c]     += p * f.x;
                acc[2 * c + 1] += p * f.y;
            }
        }
    }
    // reduce across the 8 row-groups
    #pragma unroll
    for (int o = 8; o < 64; o <<= 1) {
        #pragma unroll
        for (int i = 0; i < 8; ++i) acc[i] += __shfl_xor(acc[i], o);
    }

    if (r == 0) {
        float4* orow = (float4*)(out + ((size_t)b * M + m) * D);
        orow[2 * ci]     = make_float4(acc[0] * inv, acc[1] * inv,
                                       acc[2] * inv, acc[3] * inv);
        orow[2 * ci + 1] = make_float4(acc[4] * inv, acc[5] * inv,
                                       acc[6] * inv, acc[7] * inv);
    }
}

// ---- fallback fp32 kernel (R1 structure) if workspace too small ----
__global__ __launch_bounds__(128) void sparse_attn_f32(
    const float* __restrict__ q,
    const float* __restrict__ k,
    const float* __restrict__ v,
    const int*   __restrict__ idx,
    float*       __restrict__ out)
{
    const int blk = blockIdx.x;
    const int b = blk & 3;
    const int m = blk >> 2;
    const int t = threadIdx.x;
    const int lane = t & 63;
    const int wave = t >> 6;
    const int ci = lane & 15;
    const int r  = lane >> 4;

    __shared__ int   idx_s[W];
    __shared__ float sc_s[W];
    __shared__ float red_s[4];
    __shared__ float4 opart_s[16];

    idx_s[t] = idx[m * W + t];
    const float4 qf = ((const float4*)(q + ((size_t)b * M + m) * D))[ci];
    __syncthreads();

    const float* kb = k + (size_t)b * M * D;
    const int wbase = wave * 64;

    #pragma unroll
    for (int j = 0; j < 16; ++j) {
        const int w = wbase + j * 4 + r;
        const float4 kv = ((const float4*)(kb + (size_t)idx_s[w] * D))[ci];
        float part = kv.x * qf.x + kv.y * qf.y + kv.z * qf.z + kv.w * qf.w;
        part += __shfl_xor(part, 1);
        part += __shfl_xor(part, 2);
        part += __shfl_xor(part, 4);
        part += __shfl_xor(part, 8);
        if (ci == 0) sc_s[w] = part;
    }
    __syncthreads();

    float logit = sc_s[t];
    float mx = logit;
    #pragma unroll
    for (int o = 1; o < 64; o <<= 1) mx = fmaxf(mx, __shfl_xor(mx, o));
    if (lane == 0) red_s[wave] = mx;
    __syncthreads();
    mx = fmaxf(red_s[0], red_s[1]);
    float e = __expf(logit - mx);
    float sm = e;
    #pragma unroll
    for (int o = 1; o < 64; o <<= 1) sm += __shfl_xor(sm, o);
    if (lane == 0) red_s[2 + wave] = sm;
    __syncthreads();
    const float inv_denom = 1.0f / (red_s[2] + red_s[3]);
    sc_s[t] = e * inv_denom;
    __syncthreads();

    const float* vb = v + (size_t)b * M * D;
    float4 acc = {0.f, 0.f, 0.f, 0.f};
    #pragma unroll
    for (int j = 0; j < 16; ++j) {
        const int w = wbase + j * 4 + r;
        const float p = sc_s[w];
        const float4 vv = ((const float4*)(vb + (size_t)idx_s[w] * D))[ci];
        acc.x += p * vv.x; acc.y += p * vv.y;
        acc.z += p * vv.z; acc.w += p * vv.w;
    }
    acc.x += __shfl_xor(acc.x, 16); acc.y += __shfl_xor(acc.y, 16);
    acc.z += __shfl_xor(acc.z, 16); acc.w += __shfl_xor(acc.w, 16);
    acc.x += __shfl_xor(acc.x, 32); acc.y += __shfl_xor(acc.y, 32);
    acc.z += __shfl_xor(acc.z, 32); acc.w += __shfl_xor(acc.w, 32);

    if (wave == 0 && r == 0) opart_s[ci] = acc;
    __syncthreads();
    if (wave == 1 && r == 0) {
        const float4 o0 = opart_s[ci];
        float4 res;
        res.x = o0.x + acc.x; res.y = o0.y + acc.y;
        res.z = o0.z + acc.z; res.w = o0.w + acc.w;
        ((float4*)(out + ((size_t)b * M + m) * D))[ci] = res;
    }
}

extern "C" void kernel_launch(void* const* d_in, const int* in_sizes, int n_in,
                              void* d_out, int out_size, void* d_ws, size_t ws_size,
                              hipStream_t stream) {
    const float* q = (const float*)d_in[0];
    const float* k = (const float*)d_in[1];
    const float* v = (const float*)d_in[2];
    const int* idx = (const int*)d_in[3];
    float* out = (float*)d_out;

    const size_t need = (size_t)2 * NELEM * sizeof(__half);  // 4 MiB
    if (ws_size >= need) {
        __half* kh = (__half*)d_ws;
        __half* vh = kh + NELEM;
        const int n4 = NELEM / 4;
        const int cblk = (2 * n4 + 255) / 256;
        cvt_f32_f16_2<<<cblk, 256, 0, stream>>>((const float4*)k, (const float4*)v,
                                                (__half2*)kh, (__half2*)vh, n4);
        // one wave per (b,m) row; 4 m-rows (one b) per 256-thread block
        // grid = B*M/4 blocks (4 rows per block) -- NOT B*M (R3 OOB bug)
        sparse_attn_f16<<<B * M / 4, 256, 0, stream>>>(q, kh, vh, idx, out);
    } else {
        sparse_attn_f32<<<B * M, 128, 0, stream>>>(q, k, v, idx, out);
    }
}